// Round 5
// baseline (183.533 us; speedup 1.0000x reference)
//
#include <hip/hip_runtime.h>

#define N_NODES 100000
#define N_EDGES 600000
#define D 128
#define K2 256          // stacked K = [agg | x]
#define SCAN_TILE 1024
#define NBLK 98         // ceil(N_NODES / SCAN_TILE)

typedef __attribute__((ext_vector_type(8))) short short8;
typedef __attribute__((ext_vector_type(4))) float f32x4;

__device__ __forceinline__ unsigned short f2bf(float f) {
    union { float f; unsigned u; } v; v.f = f;
    unsigned u = v.u;
    u += 0x7FFFu + ((u >> 16) & 1u);     // round-to-nearest-even
    return (unsigned short)(u >> 16);
}

__device__ __forceinline__ float bf_lo(unsigned u) {
    union { unsigned u; float f; } v; v.u = u << 16; return v.f;
}
__device__ __forceinline__ float bf_hi(unsigned u) {
    union { unsigned u; float f; } v; v.u = u & 0xFFFF0000u; return v.f;
}

// ---------------------------------------------------------------------------
// Counting sort: hist -> 3-phase scan -> scatter_idx
// ---------------------------------------------------------------------------
__global__ void hist_kernel(const int* __restrict__ ei, int* __restrict__ counts) {
    int e = blockIdx.x * blockDim.x + threadIdx.x;
    if (e >= N_EDGES) return;
    atomicAdd(&counts[ei[N_EDGES + e]], 1);
}

__global__ __launch_bounds__(SCAN_TILE) void tile_sum_kernel(
        const int* __restrict__ counts, int* __restrict__ blockSums) {
    __shared__ int sh[SCAN_TILE];
    int t = threadIdx.x;
    int gid = blockIdx.x * SCAN_TILE + t;
    sh[t] = (gid < N_NODES) ? counts[gid] : 0;
    __syncthreads();
    for (int off = SCAN_TILE / 2; off > 0; off >>= 1) {
        if (t < off) sh[t] += sh[t + off];
        __syncthreads();
    }
    if (t == 0) blockSums[blockIdx.x] = sh[0];
}

__global__ void scan_blocks_kernel(const int* __restrict__ blockSums,
                                   int* __restrict__ blockOff) {
    __shared__ int sh[128];
    int t = threadIdx.x;
    int v = (t < NBLK) ? blockSums[t] : 0;
    sh[t] = v;
    __syncthreads();
    for (int off = 1; off < 128; off <<= 1) {
        int u = (t >= off) ? sh[t - off] : 0;
        __syncthreads();
        sh[t] += u;
        __syncthreads();
    }
    if (t < NBLK) blockOff[t] = sh[t] - v;
}

__global__ __launch_bounds__(SCAN_TILE) void scan_tile_kernel(
        const int* __restrict__ counts, const int* __restrict__ blockOff,
        int* __restrict__ offsets, int* __restrict__ cursor) {
    __shared__ int sh[SCAN_TILE];
    int t = threadIdx.x;
    int gid = blockIdx.x * SCAN_TILE + t;
    int v = (gid < N_NODES) ? counts[gid] : 0;
    sh[t] = v;
    __syncthreads();
    for (int off = 1; off < SCAN_TILE; off <<= 1) {
        int u = (t >= off) ? sh[t - off] : 0;
        __syncthreads();
        sh[t] += u;
        __syncthreads();
    }
    int excl = sh[t] - v + blockOff[blockIdx.x];
    if (gid < N_NODES) {
        offsets[gid] = excl;
        cursor[gid] = excl;
    }
    if (gid == N_NODES - 1) offsets[N_NODES] = excl + v;
}

__global__ void scatter_idx_kernel(const int* __restrict__ ei,
                                   int* __restrict__ cursor,
                                   int* __restrict__ srcSorted) {
    int e = blockIdx.x * blockDim.x + threadIdx.x;
    if (e >= N_EDGES) return;
    int s = ei[e];
    int t = ei[N_EDGES + e];
    int pos = atomicAdd(&cursor[t], 1);
    srcSorted[pos] = s;
}

// ---------------------------------------------------------------------------
// convert_x: x fp32 -> Amat[:,128:256) bf16.  MUST run before seg_sum (its
// gather source).  1 thread = 8 contiguous elems.
// ---------------------------------------------------------------------------
__global__ void convert_x_kernel(const float* __restrict__ x,
                                 unsigned short* __restrict__ Amat) {
    int t = blockIdx.x * blockDim.x + threadIdx.x;
    if (t >= N_NODES * 16) return;
    int n = t >> 4, c8 = (t & 15) * 8;
    const float4* p = (const float4*)&x[(size_t)n * D + c8];
    float4 v0 = p[0], v1 = p[1];
    uint4 o;
    o.x = (unsigned)f2bf(v0.x) | ((unsigned)f2bf(v0.y) << 16);
    o.y = (unsigned)f2bf(v0.z) | ((unsigned)f2bf(v0.w) << 16);
    o.z = (unsigned)f2bf(v1.x) | ((unsigned)f2bf(v1.y) << 16);
    o.w = (unsigned)f2bf(v1.z) | ((unsigned)f2bf(v1.w) << 16);
    *(uint4*)&Amat[(size_t)n * K2 + 128 + c8] = o;
}

// ---------------------------------------------------------------------------
// seg_sum: one wave per node, lane = 2 bf16 cols (4B load per edge).
// Gathers from the bf16 x-half of Amat (256 B/row, ~25.6 MB working set ->
// L3-friendly, half the fp32 traffic).  fp32 accumulate, bf16 out to the
// agg-half.  Reads cols [128,256) of other rows, writes cols [0,128) of own
// row: disjoint regions, race-free.
// ---------------------------------------------------------------------------
__global__ void seg_sum_kernel(const int* __restrict__ offsets,
                               const int* __restrict__ srcSorted,
                               unsigned short* __restrict__ Amat) {
    int wid = (blockIdx.x * blockDim.x + threadIdx.x) >> 6;
    if (wid >= N_NODES) return;
    int lane = threadIdx.x & 63;
    int beg = offsets[wid], end = offsets[wid + 1];
    float2 acc = make_float2(0.f, 0.f);
    int p = beg;
    for (; p + 3 < end; p += 4) {       // 4-edge unroll: 4 independent gathers
        int s0 = srcSorted[p],     s1 = srcSorted[p + 1];
        int s2 = srcSorted[p + 2], s3 = srcSorted[p + 3];
        unsigned u0 = *(const unsigned*)&Amat[(size_t)s0 * K2 + 128 + lane * 2];
        unsigned u1 = *(const unsigned*)&Amat[(size_t)s1 * K2 + 128 + lane * 2];
        unsigned u2 = *(const unsigned*)&Amat[(size_t)s2 * K2 + 128 + lane * 2];
        unsigned u3 = *(const unsigned*)&Amat[(size_t)s3 * K2 + 128 + lane * 2];
        acc.x += (bf_lo(u0) + bf_lo(u1)) + (bf_lo(u2) + bf_lo(u3));
        acc.y += (bf_hi(u0) + bf_hi(u1)) + (bf_hi(u2) + bf_hi(u3));
    }
    for (; p < end; ++p) {
        int s0 = srcSorted[p];
        unsigned u0 = *(const unsigned*)&Amat[(size_t)s0 * K2 + 128 + lane * 2];
        acc.x += bf_lo(u0);
        acc.y += bf_hi(u0);
    }
    unsigned pack = (unsigned)f2bf(acc.x) | ((unsigned)f2bf(acc.y) << 16);
    *(unsigned*)&Amat[(size_t)wid * K2 + lane * 2] = pack;
}

// ---------------------------------------------------------------------------
// wprep: pack stacked weights [Wrel;Wroot] into MFMA B-fragment order, bf16.
// ---------------------------------------------------------------------------
__global__ void wprep_kernel(const float* __restrict__ Wrel,
                             const float* __restrict__ Wroot,
                             unsigned short* __restrict__ Wfrag) {
    int slot = blockIdx.x * blockDim.x + threadIdx.x;
    if (slot >= 4096) return;
    int lane = slot & 63;
    int ks = (slot >> 6) & 7;
    int ct = slot >> 9;
    int m = ct * 16 + (lane & 15);
    int k = ks * 32 + (lane >> 4) * 8;
    const float* src = (k < 128) ? &Wrel[(size_t)m * 128 + k]
                                 : &Wroot[(size_t)m * 128 + (k - 128)];
    uint4 o;
    o.x = (unsigned)f2bf(src[0]) | ((unsigned)f2bf(src[1]) << 16);
    o.y = (unsigned)f2bf(src[2]) | ((unsigned)f2bf(src[3]) << 16);
    o.z = (unsigned)f2bf(src[4]) | ((unsigned)f2bf(src[5]) << 16);
    o.w = (unsigned)f2bf(src[6]) | ((unsigned)f2bf(src[7]) << 16);
    *(uint4*)&Wfrag[(size_t)slot * 8] = o;
}

// ---------------------------------------------------------------------------
// gemm_mfma: out[n][m] = Amat[n][:] (bf16, K=256) . Wfrag + brel[m], fp32 out.
// Grid-stride over 128-row chunks: Wlds staged ONCE per block (512 blocks
// instead of 782 -> ~35% less redundant weight staging).
// ---------------------------------------------------------------------------
#define GEMM_BLOCKS 512
__global__ __launch_bounds__(256, 2) void gemm_mfma(
        const unsigned short* __restrict__ Amat,
        const unsigned short* __restrict__ Wfrag,
        const float* __restrict__ brel,
        float* __restrict__ out) {
    __shared__ short8 Wlds[4096];   // 64 KB
    int tid = threadIdx.x;
    for (int i = tid; i < 4096; i += 256)
        Wlds[i] = *(const short8*)&Wfrag[(size_t)i * 8];
    __syncthreads();

    int lane = tid & 63;
    int w = tid >> 6;
    int n16 = lane & 15, kg = lane >> 4;
    const int nChunks = (N_NODES + 127) / 128;   // 782

    for (int chunk = blockIdx.x; chunk < nChunks; chunk += GEMM_BLOCKS) {
        long row0 = (long)chunk * 128 + w * 32;

        long r0 = row0 + n16;
        long r1 = row0 + 16 + n16;
        long cr0 = (r0 < N_NODES) ? r0 : (N_NODES - 1);
        long cr1 = (r1 < N_NODES) ? r1 : (N_NODES - 1);
        const short8* a0p = (const short8*)(Amat + cr0 * K2 + kg * 8);
        const short8* a1p = (const short8*)(Amat + cr1 * K2 + kg * 8);

        f32x4 acc[2][8];
#pragma unroll
        for (int h = 0; h < 2; ++h)
#pragma unroll
            for (int ct = 0; ct < 8; ++ct)
                acc[h][ct] = (f32x4){0.f, 0.f, 0.f, 0.f};

        short8 a0 = a0p[0], a1 = a1p[0];
#pragma unroll
        for (int ks = 0; ks < 8; ++ks) {
            short8 na0, na1;
            if (ks < 7) {               // prefetch next K-step
                na0 = a0p[(ks + 1) * 4];
                na1 = a1p[(ks + 1) * 4];
            }
#pragma unroll
            for (int ct = 0; ct < 8; ++ct) {
                short8 b = Wlds[(ct * 8 + ks) * 64 + lane];
                acc[0][ct] = __builtin_amdgcn_mfma_f32_16x16x32_bf16(a0, b, acc[0][ct], 0, 0, 0);
                acc[1][ct] = __builtin_amdgcn_mfma_f32_16x16x32_bf16(a1, b, acc[1][ct], 0, 0, 0);
            }
            a0 = na0; a1 = na1;
        }

        // D layout (measured m89): col = lane&15, row = 4*(lane>>4) + reg.
#pragma unroll
        for (int h = 0; h < 2; ++h) {
            long rb = row0 + h * 16 + 4 * kg;
#pragma unroll
            for (int ct = 0; ct < 8; ++ct) {
                float bias = brel[ct * 16 + n16];
#pragma unroll
                for (int r = 0; r < 4; ++r) {
                    long row = rb + r;
                    if (row < N_NODES)
                        out[row * 128 + ct * 16 + n16] = acc[h][ct][r] + bias;
                }
            }
        }
    }
}

// ---------------------------------------------------------------------------
// Fallback (ws too small): atomic scatter + fp32 GEMM (round-1 path).
// ---------------------------------------------------------------------------
__global__ void scatter_kernel(const float* __restrict__ x,
                               const int* __restrict__ ei,
                               float* __restrict__ agg) {
    int gid = blockIdx.x * blockDim.x + threadIdx.x;
    int e = gid >> 5;
    if (e >= N_EDGES) return;
    int q = (gid & 31) * 4;
    int s = ei[e];
    int t = ei[N_EDGES + e];
    float4 v = *(const float4*)&x[(size_t)s * D + q];
    float* ap = &agg[(size_t)t * D + q];
    atomicAdd(ap + 0, v.x);
    atomicAdd(ap + 1, v.y);
    atomicAdd(ap + 2, v.z);
    atomicAdd(ap + 3, v.w);
}

__global__ __launch_bounds__(256, 1) void fused_gemm(
        const float* __restrict__ agg, const float* __restrict__ x,
        const float* __restrict__ Wrel, const float* __restrict__ brel,
        const float* __restrict__ Wroot, float* __restrict__ out,
        int nChunks) {
    __shared__ float W2t[256][128];
    __shared__ float rows[16][256];
    int tid = threadIdx.x;
    for (int idx = tid; idx < 256 * 128; idx += 256) {
        int k = idx >> 7, m = idx & 127;
        W2t[k][m] = (k < 128) ? Wrel[m * 128 + k] : Wroot[m * 128 + (k - 128)];
    }
    __syncthreads();
    int mq = tid & 31, rg = tid >> 5, m4 = mq * 4;
    for (int chunk = blockIdx.x; chunk < nChunks; chunk += gridDim.x) {
        size_t row0 = (size_t)chunk * 16;
        __syncthreads();
        for (int j = 0; j < 4; ++j) {
            int i = (tid + j * 256) * 4;
            int r = i >> 8, c = i & 255;
            float4 v;
            if (c < 128) v = *(const float4*)&agg[(row0 + r) * D + c];
            else         v = *(const float4*)&x[(row0 + r) * D + (c - 128)];
            *(float4*)&rows[r][c] = v;
        }
        __syncthreads();
        float4 acc0 = make_float4(0, 0, 0, 0), acc1 = make_float4(0, 0, 0, 0);
#pragma unroll 8
        for (int k = 0; k < 256; ++k) {
            float4 wv = *(const float4*)&W2t[k][m4];
            float A0 = rows[rg][k], A1 = rows[rg + 8][k];
            acc0.x = fmaf(A0, wv.x, acc0.x); acc0.y = fmaf(A0, wv.y, acc0.y);
            acc0.z = fmaf(A0, wv.z, acc0.z); acc0.w = fmaf(A0, wv.w, acc0.w);
            acc1.x = fmaf(A1, wv.x, acc1.x); acc1.y = fmaf(A1, wv.y, acc1.y);
            acc1.z = fmaf(A1, wv.z, acc1.z); acc1.w = fmaf(A1, wv.w, acc1.w);
        }
        float4 b = *(const float4*)&brel[m4];
        *(float4*)&out[(row0 + rg) * D + m4] =
            make_float4(acc0.x + b.x, acc0.y + b.y, acc0.z + b.z, acc0.w + b.w);
        *(float4*)&out[(row0 + rg + 8) * D + m4] =
            make_float4(acc1.x + b.x, acc1.y + b.y, acc1.z + b.z, acc1.w + b.w);
    }
}

extern "C" void kernel_launch(void* const* d_in, const int* in_sizes, int n_in,
                              void* d_out, int out_size, void* d_ws, size_t ws_size,
                              hipStream_t stream) {
    const float* x     = (const float*)d_in[0];
    const int*   ei    = (const int*)d_in[1];
    const float* Wrel  = (const float*)d_in[2];
    const float* brel  = (const float*)d_in[3];
    const float* Wroot = (const float*)d_in[4];
    float* out = (float*)d_out;

    const size_t amatBytes = (size_t)N_NODES * K2 * sizeof(unsigned short); // 51.2 MB
    const size_t offBytes  = (size_t)(N_NODES + 1) * sizeof(int);
    const size_t curBytes  = (size_t)N_NODES * sizeof(int);
    const size_t srcBytes  = (size_t)N_EDGES * sizeof(int);
    const size_t cntBytes  = (size_t)N_NODES * sizeof(int);
    const size_t blkBytes  = (size_t)NBLK * sizeof(int);
    const size_t wfBytes   = (size_t)4096 * 8 * sizeof(unsigned short);     // 64 KB
    auto align16 = [](size_t v) { return (v + 15) & ~(size_t)15; };

    size_t o_amat = 0;
    size_t o_off  = align16(o_amat + amatBytes);
    size_t o_cur  = align16(o_off + offBytes);
    size_t o_src  = align16(o_cur + curBytes);
    size_t o_cnt  = align16(o_src + srcBytes);
    size_t o_bs   = align16(o_cnt + cntBytes);
    size_t o_bo   = align16(o_bs + blkBytes);
    size_t o_wf   = align16(o_bo + blkBytes);
    size_t total  = o_wf + wfBytes;

    if (ws_size >= total) {
        char* ws = (char*)d_ws;
        unsigned short* Amat  = (unsigned short*)(ws + o_amat);
        int*   offsets   = (int*)(ws + o_off);
        int*   cursor    = (int*)(ws + o_cur);
        int*   srcSorted = (int*)(ws + o_src);
        int*   counts    = (int*)(ws + o_cnt);
        int*   blockSums = (int*)(ws + o_bs);
        int*   blockOff  = (int*)(ws + o_bo);
        unsigned short* Wfrag = (unsigned short*)(ws + o_wf);

        hipMemsetAsync(counts, 0, cntBytes, stream);
        hist_kernel<<<(N_EDGES + 255) / 256, 256, 0, stream>>>(ei, counts);
        wprep_kernel<<<16, 256, 0, stream>>>(Wrel, Wroot, Wfrag);
        convert_x_kernel<<<(N_NODES * 16 + 255) / 256, 256, 0, stream>>>(x, Amat);
        tile_sum_kernel<<<NBLK, SCAN_TILE, 0, stream>>>(counts, blockSums);
        scan_blocks_kernel<<<1, 128, 0, stream>>>(blockSums, blockOff);
        scan_tile_kernel<<<NBLK, SCAN_TILE, 0, stream>>>(counts, blockOff, offsets, cursor);
        scatter_idx_kernel<<<(N_EDGES + 255) / 256, 256, 0, stream>>>(ei, cursor, srcSorted);
        seg_sum_kernel<<<(N_NODES * 64 + 255) / 256, 256, 0, stream>>>(offsets, srcSorted, Amat);
        gemm_mfma<<<GEMM_BLOCKS, 256, 0, stream>>>(Amat, Wfrag, brel, out);
    } else {
        // Fallback: atomic scatter + fp32 GEMM.
        float* agg = (ws_size >= (size_t)N_NODES * D * sizeof(float)) ? (float*)d_ws : out;
        hipMemsetAsync(agg, 0, (size_t)N_NODES * D * sizeof(float), stream);
        scatter_kernel<<<(N_EDGES * 32 + 255) / 256, 256, 0, stream>>>(x, ei, agg);
        fused_gemm<<<256, 256, 0, stream>>>(agg, x, Wrel, brel, Wroot, out,
                                            N_NODES / 16);
    }
}

// Round 6
// 159.244 us; speedup vs baseline: 1.1525x; 1.1525x over previous
//
#include <hip/hip_runtime.h>

#define N_NODES 100000
#define N_EDGES 600000
#define D 128
#define K2 256          // stacked K = [agg | x]
#define SCAN_TILE 1024
#define NBLK 98         // ceil(N_NODES / SCAN_TILE)

typedef __attribute__((ext_vector_type(8))) short short8;
typedef __attribute__((ext_vector_type(4))) float f32x4;

__device__ __forceinline__ unsigned short f2bf(float f) {
    union { float f; unsigned u; } v; v.f = f;
    unsigned u = v.u;
    u += 0x7FFFu + ((u >> 16) & 1u);     // round-to-nearest-even
    return (unsigned short)(u >> 16);
}

__device__ __forceinline__ float bf_lo(unsigned u) {
    union { unsigned u; float f; } v; v.u = u << 16; return v.f;
}
__device__ __forceinline__ float bf_hi(unsigned u) {
    union { unsigned u; float f; } v; v.u = u & 0xFFFF0000u; return v.f;
}

// ---------------------------------------------------------------------------
// Counting sort: hist -> 3-phase scan -> scatter_idx
// ---------------------------------------------------------------------------
__global__ void hist_kernel(const int* __restrict__ ei, int* __restrict__ counts) {
    int e = blockIdx.x * blockDim.x + threadIdx.x;
    if (e >= N_EDGES) return;
    atomicAdd(&counts[ei[N_EDGES + e]], 1);
}

__global__ __launch_bounds__(SCAN_TILE) void tile_sum_kernel(
        const int* __restrict__ counts, int* __restrict__ blockSums) {
    __shared__ int sh[SCAN_TILE];
    int t = threadIdx.x;
    int gid = blockIdx.x * SCAN_TILE + t;
    sh[t] = (gid < N_NODES) ? counts[gid] : 0;
    __syncthreads();
    for (int off = SCAN_TILE / 2; off > 0; off >>= 1) {
        if (t < off) sh[t] += sh[t + off];
        __syncthreads();
    }
    if (t == 0) blockSums[blockIdx.x] = sh[0];
}

__global__ void scan_blocks_kernel(const int* __restrict__ blockSums,
                                   int* __restrict__ blockOff) {
    __shared__ int sh[128];
    int t = threadIdx.x;
    int v = (t < NBLK) ? blockSums[t] : 0;
    sh[t] = v;
    __syncthreads();
    for (int off = 1; off < 128; off <<= 1) {
        int u = (t >= off) ? sh[t - off] : 0;
        __syncthreads();
        sh[t] += u;
        __syncthreads();
    }
    if (t < NBLK) blockOff[t] = sh[t] - v;
}

__global__ __launch_bounds__(SCAN_TILE) void scan_tile_kernel(
        const int* __restrict__ counts, const int* __restrict__ blockOff,
        int* __restrict__ offsets, int* __restrict__ cursor) {
    __shared__ int sh[SCAN_TILE];
    int t = threadIdx.x;
    int gid = blockIdx.x * SCAN_TILE + t;
    int v = (gid < N_NODES) ? counts[gid] : 0;
    sh[t] = v;
    __syncthreads();
    for (int off = 1; off < SCAN_TILE; off <<= 1) {
        int u = (t >= off) ? sh[t - off] : 0;
        __syncthreads();
        sh[t] += u;
        __syncthreads();
    }
    int excl = sh[t] - v + blockOff[blockIdx.x];
    if (gid < N_NODES) {
        offsets[gid] = excl;
        cursor[gid] = excl;
    }
    if (gid == N_NODES - 1) offsets[N_NODES] = excl + v;
}

__global__ void scatter_idx_kernel(const int* __restrict__ ei,
                                   int* __restrict__ cursor,
                                   int* __restrict__ srcSorted) {
    int e = blockIdx.x * blockDim.x + threadIdx.x;
    if (e >= N_EDGES) return;
    int s = ei[e];
    int t = ei[N_EDGES + e];
    int pos = atomicAdd(&cursor[t], 1);
    srcSorted[pos] = s;
}

// ---------------------------------------------------------------------------
// convert_x: x fp32 -> Amat[:,128:256) bf16.  MUST run before seg_sum.
// ---------------------------------------------------------------------------
__global__ void convert_x_kernel(const float* __restrict__ x,
                                 unsigned short* __restrict__ Amat) {
    int t = blockIdx.x * blockDim.x + threadIdx.x;
    if (t >= N_NODES * 16) return;
    int n = t >> 4, c8 = (t & 15) * 8;
    const float4* p = (const float4*)&x[(size_t)n * D + c8];
    float4 v0 = p[0], v1 = p[1];
    uint4 o;
    o.x = (unsigned)f2bf(v0.x) | ((unsigned)f2bf(v0.y) << 16);
    o.y = (unsigned)f2bf(v0.z) | ((unsigned)f2bf(v0.w) << 16);
    o.z = (unsigned)f2bf(v1.x) | ((unsigned)f2bf(v1.y) << 16);
    o.w = (unsigned)f2bf(v1.z) | ((unsigned)f2bf(v1.w) << 16);
    *(uint4*)&Amat[(size_t)n * K2 + 128 + c8] = o;
}

// ---------------------------------------------------------------------------
// seg_sum v2: one wave per node; TWO edges in flight per iteration.
// Lanes 0-31 handle edge p (cols (lane&31)*4, 8B load), lanes 32-63 edge p+1.
// fp32 partial acc per half; halves combined with shfl_xor(32) at the end.
// Reads cols [128,256) of other rows, writes cols [0,128) of own row.
// ---------------------------------------------------------------------------
__global__ void seg_sum_kernel(const int* __restrict__ offsets,
                               const int* __restrict__ srcSorted,
                               unsigned short* __restrict__ Amat) {
    int wid = (blockIdx.x * blockDim.x + threadIdx.x) >> 6;
    if (wid >= N_NODES) return;
    int lane = threadIdx.x & 63;
    int half = lane >> 5;
    int cq = (lane & 31) * 4;           // 4 bf16 cols = 8 B per lane
    int beg = offsets[wid], end = offsets[wid + 1];
    float4 acc = make_float4(0.f, 0.f, 0.f, 0.f);
    int p = beg + half;
    for (; p + 2 < end; p += 4) {       // 2 gathers in flight per half
        int s0 = srcSorted[p], s1 = srcSorted[p + 2];
        uint2 u0 = *(const uint2*)&Amat[(size_t)s0 * K2 + 128 + cq];
        uint2 u1 = *(const uint2*)&Amat[(size_t)s1 * K2 + 128 + cq];
        acc.x += bf_lo(u0.x) + bf_lo(u1.x);
        acc.y += bf_hi(u0.x) + bf_hi(u1.x);
        acc.z += bf_lo(u0.y) + bf_lo(u1.y);
        acc.w += bf_hi(u0.y) + bf_hi(u1.y);
    }
    if (p < end) {
        int s0 = srcSorted[p];
        uint2 u0 = *(const uint2*)&Amat[(size_t)s0 * K2 + 128 + cq];
        acc.x += bf_lo(u0.x);
        acc.y += bf_hi(u0.x);
        acc.z += bf_lo(u0.y);
        acc.w += bf_hi(u0.y);
    }
    // combine the two halves (same cq in both)
    acc.x += __shfl_xor(acc.x, 32);
    acc.y += __shfl_xor(acc.y, 32);
    acc.z += __shfl_xor(acc.z, 32);
    acc.w += __shfl_xor(acc.w, 32);
    if (half == 0) {
        uint2 o;
        o.x = (unsigned)f2bf(acc.x) | ((unsigned)f2bf(acc.y) << 16);
        o.y = (unsigned)f2bf(acc.z) | ((unsigned)f2bf(acc.w) << 16);
        *(uint2*)&Amat[(size_t)wid * K2 + cq] = o;
    }
}

// ---------------------------------------------------------------------------
// wprep: pack stacked weights [Wrel;Wroot] into MFMA B-fragment order, bf16.
// ---------------------------------------------------------------------------
__global__ void wprep_kernel(const float* __restrict__ Wrel,
                             const float* __restrict__ Wroot,
                             unsigned short* __restrict__ Wfrag) {
    int slot = blockIdx.x * blockDim.x + threadIdx.x;
    if (slot >= 4096) return;
    int lane = slot & 63;
    int ks = (slot >> 6) & 7;
    int ct = slot >> 9;
    int m = ct * 16 + (lane & 15);
    int k = ks * 32 + (lane >> 4) * 8;
    const float* src = (k < 128) ? &Wrel[(size_t)m * 128 + k]
                                 : &Wroot[(size_t)m * 128 + (k - 128)];
    uint4 o;
    o.x = (unsigned)f2bf(src[0]) | ((unsigned)f2bf(src[1]) << 16);
    o.y = (unsigned)f2bf(src[2]) | ((unsigned)f2bf(src[3]) << 16);
    o.z = (unsigned)f2bf(src[4]) | ((unsigned)f2bf(src[5]) << 16);
    o.w = (unsigned)f2bf(src[6]) | ((unsigned)f2bf(src[7]) << 16);
    *(uint4*)&Wfrag[(size_t)slot * 8] = o;
}

// ---------------------------------------------------------------------------
// gemm_mfma v2: out[n][m] = Amat[n][:] (bf16, K=256) . W + brel[m], fp32 out.
// One 128-row chunk per block (782 blocks, balanced).
//  - ALL 8 K-steps of A preloaded (16 dwordx4 in flight/wave -> MLP).
//  - Epilogue: acc staged into the (reused) 64 KB W-LDS with XOR swizzle,
//    then fully-coalesced float4 stores (fixes the 2.3x WRITE RMW blowup).
// ---------------------------------------------------------------------------
__global__ __launch_bounds__(256, 2) void gemm_mfma(
        const unsigned short* __restrict__ Amat,
        const unsigned short* __restrict__ Wfrag,
        const float* __restrict__ brel,
        float* __restrict__ out) {
    __shared__ __align__(16) char smem[65536];
    short8* Wlds = (short8*)smem;
    float*  So   = (float*)smem;

    int tid = threadIdx.x;
    for (int i = tid; i < 4096; i += 256)
        Wlds[i] = *(const short8*)&Wfrag[(size_t)i * 8];
    __syncthreads();

    int lane = tid & 63;
    int w = tid >> 6;
    int n16 = lane & 15, kg = lane >> 4;
    long rowB = (long)blockIdx.x * 128;       // block's first row
    long row0 = rowB + w * 32;                // wave's first row

    long r0 = row0 + n16;
    long r1 = row0 + 16 + n16;
    long cr0 = (r0 < N_NODES) ? r0 : (N_NODES - 1);
    long cr1 = (r1 < N_NODES) ? r1 : (N_NODES - 1);
    const short8* a0p = (const short8*)(Amat + cr0 * K2 + kg * 8);
    const short8* a1p = (const short8*)(Amat + cr1 * K2 + kg * 8);

    // Preload the full K=256 strip: 16 independent dwordx4 loads in flight.
    short8 a0v[8], a1v[8];
#pragma unroll
    for (int ks = 0; ks < 8; ++ks) {
        a0v[ks] = a0p[ks * 4];
        a1v[ks] = a1p[ks * 4];
    }

    f32x4 acc[2][8];
#pragma unroll
    for (int h = 0; h < 2; ++h)
#pragma unroll
        for (int ct = 0; ct < 8; ++ct)
            acc[h][ct] = (f32x4){0.f, 0.f, 0.f, 0.f};

#pragma unroll
    for (int ks = 0; ks < 8; ++ks) {
#pragma unroll
        for (int ct = 0; ct < 8; ++ct) {
            short8 b = Wlds[(ct * 8 + ks) * 64 + lane];
            acc[0][ct] = __builtin_amdgcn_mfma_f32_16x16x32_bf16(a0v[ks], b, acc[0][ct], 0, 0, 0);
            acc[1][ct] = __builtin_amdgcn_mfma_f32_16x16x32_bf16(a1v[ks], b, acc[1][ct], 0, 0, 0);
        }
    }

    // ---- epilogue: LDS transpose (reuse W space) + coalesced stores ----
    __syncthreads();   // all waves done reading Wlds
    // D layout (m89): col = lane&15, row = 4*(lane>>4) + reg.
#pragma unroll
    for (int h = 0; h < 2; ++h)
#pragma unroll
        for (int ct = 0; ct < 8; ++ct) {
            float bias = brel[ct * 16 + n16];
#pragma unroll
            for (int r = 0; r < 4; ++r) {
                int lrow = w * 32 + h * 16 + kg * 4 + r;
                int col = ct * 16 + n16;
                So[lrow * 128 + (col ^ ((lrow & 7) << 2))] = acc[h][ct][r] + bias;
            }
        }
    __syncthreads();

    // Coalesced write-out: g-th float4 of the chunk; 64 lanes = 1 KB contig.
#pragma unroll
    for (int j = 0; j < 16; ++j) {
        int g = tid + j * 256;
        int lrow = g >> 5;
        int q = g & 31;
        long grow = rowB + lrow;
        if (grow < N_NODES) {
            float4 v = *(float4*)&So[lrow * 128 + ((q * 4) ^ ((lrow & 7) << 2))];
            *(float4*)&out[grow * 128 + q * 4] = v;
        }
    }
}

// ---------------------------------------------------------------------------
// Fallback (ws too small): atomic scatter + fp32 GEMM (round-1 path).
// ---------------------------------------------------------------------------
__global__ void scatter_kernel(const float* __restrict__ x,
                               const int* __restrict__ ei,
                               float* __restrict__ agg) {
    int gid = blockIdx.x * blockDim.x + threadIdx.x;
    int e = gid >> 5;
    if (e >= N_EDGES) return;
    int q = (gid & 31) * 4;
    int s = ei[e];
    int t = ei[N_EDGES + e];
    float4 v = *(const float4*)&x[(size_t)s * D + q];
    float* ap = &agg[(size_t)t * D + q];
    atomicAdd(ap + 0, v.x);
    atomicAdd(ap + 1, v.y);
    atomicAdd(ap + 2, v.z);
    atomicAdd(ap + 3, v.w);
}

__global__ __launch_bounds__(256, 1) void fused_gemm(
        const float* __restrict__ agg, const float* __restrict__ x,
        const float* __restrict__ Wrel, const float* __restrict__ brel,
        const float* __restrict__ Wroot, float* __restrict__ out,
        int nChunks) {
    __shared__ float W2t[256][128];
    __shared__ float rows[16][256];
    int tid = threadIdx.x;
    for (int idx = tid; idx < 256 * 128; idx += 256) {
        int k = idx >> 7, m = idx & 127;
        W2t[k][m] = (k < 128) ? Wrel[m * 128 + k] : Wroot[m * 128 + (k - 128)];
    }
    __syncthreads();
    int mq = tid & 31, rg = tid >> 5, m4 = mq * 4;
    for (int chunk = blockIdx.x; chunk < nChunks; chunk += gridDim.x) {
        size_t row0 = (size_t)chunk * 16;
        __syncthreads();
        for (int j = 0; j < 4; ++j) {
            int i = (tid + j * 256) * 4;
            int r = i >> 8, c = i & 255;
            float4 v;
            if (c < 128) v = *(const float4*)&agg[(row0 + r) * D + c];
            else         v = *(const float4*)&x[(row0 + r) * D + (c - 128)];
            *(float4*)&rows[r][c] = v;
        }
        __syncthreads();
        float4 acc0 = make_float4(0, 0, 0, 0), acc1 = make_float4(0, 0, 0, 0);
#pragma unroll 8
        for (int k = 0; k < 256; ++k) {
            float4 wv = *(const float4*)&W2t[k][m4];
            float A0 = rows[rg][k], A1 = rows[rg + 8][k];
            acc0.x = fmaf(A0, wv.x, acc0.x); acc0.y = fmaf(A0, wv.y, acc0.y);
            acc0.z = fmaf(A0, wv.z, acc0.z); acc0.w = fmaf(A0, wv.w, acc0.w);
            acc1.x = fmaf(A1, wv.x, acc1.x); acc1.y = fmaf(A1, wv.y, acc1.y);
            acc1.z = fmaf(A1, wv.z, acc1.z); acc1.w = fmaf(A1, wv.w, acc1.w);
        }
        float4 b = *(const float4*)&brel[m4];
        *(float4*)&out[(row0 + rg) * D + m4] =
            make_float4(acc0.x + b.x, acc0.y + b.y, acc0.z + b.z, acc0.w + b.w);
        *(float4*)&out[(row0 + rg + 8) * D + m4] =
            make_float4(acc1.x + b.x, acc1.y + b.y, acc1.z + b.z, acc1.w + b.w);
    }
}

extern "C" void kernel_launch(void* const* d_in, const int* in_sizes, int n_in,
                              void* d_out, int out_size, void* d_ws, size_t ws_size,
                              hipStream_t stream) {
    const float* x     = (const float*)d_in[0];
    const int*   ei    = (const int*)d_in[1];
    const float* Wrel  = (const float*)d_in[2];
    const float* brel  = (const float*)d_in[3];
    const float* Wroot = (const float*)d_in[4];
    float* out = (float*)d_out;

    const size_t amatBytes = (size_t)N_NODES * K2 * sizeof(unsigned short); // 51.2 MB
    const size_t offBytes  = (size_t)(N_NODES + 1) * sizeof(int);
    const size_t curBytes  = (size_t)N_NODES * sizeof(int);
    const size_t srcBytes  = (size_t)N_EDGES * sizeof(int);
    const size_t cntBytes  = (size_t)N_NODES * sizeof(int);
    const size_t blkBytes  = (size_t)NBLK * sizeof(int);
    const size_t wfBytes   = (size_t)4096 * 8 * sizeof(unsigned short);     // 64 KB
    auto align16 = [](size_t v) { return (v + 15) & ~(size_t)15; };

    size_t o_amat = 0;
    size_t o_off  = align16(o_amat + amatBytes);
    size_t o_cur  = align16(o_off + offBytes);
    size_t o_src  = align16(o_cur + curBytes);
    size_t o_cnt  = align16(o_src + srcBytes);
    size_t o_bs   = align16(o_cnt + cntBytes);
    size_t o_bo   = align16(o_bs + blkBytes);
    size_t o_wf   = align16(o_bo + blkBytes);
    size_t total  = o_wf + wfBytes;

    if (ws_size >= total) {
        char* ws = (char*)d_ws;
        unsigned short* Amat  = (unsigned short*)(ws + o_amat);
        int*   offsets   = (int*)(ws + o_off);
        int*   cursor    = (int*)(ws + o_cur);
        int*   srcSorted = (int*)(ws + o_src);
        int*   counts    = (int*)(ws + o_cnt);
        int*   blockSums = (int*)(ws + o_bs);
        int*   blockOff  = (int*)(ws + o_bo);
        unsigned short* Wfrag = (unsigned short*)(ws + o_wf);

        hipMemsetAsync(counts, 0, cntBytes, stream);
        hist_kernel<<<(N_EDGES + 255) / 256, 256, 0, stream>>>(ei, counts);
        wprep_kernel<<<16, 256, 0, stream>>>(Wrel, Wroot, Wfrag);
        convert_x_kernel<<<(N_NODES * 16 + 255) / 256, 256, 0, stream>>>(x, Amat);
        tile_sum_kernel<<<NBLK, SCAN_TILE, 0, stream>>>(counts, blockSums);
        scan_blocks_kernel<<<1, 128, 0, stream>>>(blockSums, blockOff);
        scan_tile_kernel<<<NBLK, SCAN_TILE, 0, stream>>>(counts, blockOff, offsets, cursor);
        scatter_idx_kernel<<<(N_EDGES + 255) / 256, 256, 0, stream>>>(ei, cursor, srcSorted);
        seg_sum_kernel<<<(N_NODES * 64 + 255) / 256, 256, 0, stream>>>(offsets, srcSorted, Amat);
        gemm_mfma<<<(N_NODES + 127) / 128, 256, 0, stream>>>(Amat, Wfrag, brel, out);
    } else {
        // Fallback: atomic scatter + fp32 GEMM.
        float* agg = (ws_size >= (size_t)N_NODES * D * sizeof(float)) ? (float*)d_ws : out;
        hipMemsetAsync(agg, 0, (size_t)N_NODES * D * sizeof(float), stream);
        scatter_kernel<<<(N_EDGES * 32 + 255) / 256, 256, 0, stream>>>(x, ei, agg);
        fused_gemm<<<256, 256, 0, stream>>>(agg, x, Wrel, brel, Wroot, out,
                                            N_NODES / 16);
    }
}